// Round 2
// baseline (680.313 us; speedup 1.0000x reference)
//
#include <hip/hip_runtime.h>
#include <cstdint>
#include <cstddef>

#define S_TOK 8192
#define DIM   2048
#define NE    64
#define CAP   128
#define KSPLIT 2
#define BS    32   // tokens per GEMM block
#define DT    32   // D-tile per GEMM iteration

// ---- workspace layout (in floats/ints, 4B units) ----
// part  : [KSPLIT][S_TOK][NE] float  offset 0            (1,048,576)
// idx   : [S_TOK] int                offset 1,048,576
// gate  : [S_TOK] float              offset 1,056,768
// loc   : [S_TOK] int                offset 1,064,960
// me_sum: [NE] float                 offset 1,073,152
// prod  : [NE] float                 offset 1,073,216
#define OFF_PART   0
#define OFF_IDX    1048576
#define OFF_GATE   1056768
#define OFF_LOC    1064960
#define OFF_MESUM  1073152
#define OFF_PROD   1073216

// ---------------- GEMM: logits partial = x @ wg^T (split-K) ----------------
__global__ __launch_bounds__(256) void gemm_logits(
    const float* __restrict__ x, const float* __restrict__ wg,
    float* __restrict__ part)
{
    __shared__ float xs[BS][DT + 1];   // +1 pad: conflict-free scalar reads
    __shared__ float wsh[NE][DT + 1];

    const int sb  = blockIdx.x * BS;
    const int k   = blockIdx.y;                 // split-K index
    const int d0  = k * (DIM / KSPLIT);
    const int tid = threadIdx.x;

    const int s_loc = (tid >> 4) * 2;           // 0,2,...,30
    const int e_loc = (tid & 15) * 4;           // 0,4,...,60

    float acc[2][4] = {{0.f,0.f,0.f,0.f},{0.f,0.f,0.f,0.f}};

    for (int t = 0; t < DIM / KSPLIT; t += DT) {
        // load x tile: 32x32 floats, 256 threads -> 1 float4 each
        {
            const int r = tid >> 3;             // 0..31
            const int c = (tid & 7) * 4;        // 0..28
            const float4 v = *reinterpret_cast<const float4*>(
                &x[(size_t)(sb + r) * DIM + d0 + t + c]);
            xs[r][c]   = v.x; xs[r][c+1] = v.y;
            xs[r][c+2] = v.z; xs[r][c+3] = v.w;
        }
        // load wg tile: 64x32 floats -> 2 float4 each
        {
            const int r = tid >> 2;             // 0..63
            const int c = (tid & 3) * 8;        // 0,8,16,24
            const float4 v0 = *reinterpret_cast<const float4*>(
                &wg[(size_t)r * DIM + d0 + t + c]);
            const float4 v1 = *reinterpret_cast<const float4*>(
                &wg[(size_t)r * DIM + d0 + t + c + 4]);
            wsh[r][c]   = v0.x; wsh[r][c+1] = v0.y;
            wsh[r][c+2] = v0.z; wsh[r][c+3] = v0.w;
            wsh[r][c+4] = v1.x; wsh[r][c+5] = v1.y;
            wsh[r][c+6] = v1.z; wsh[r][c+7] = v1.w;
        }
        __syncthreads();
        #pragma unroll
        for (int d = 0; d < DT; ++d) {
            const float xv0 = xs[s_loc][d];
            const float xv1 = xs[s_loc + 1][d];
            const float w0 = wsh[e_loc][d];
            const float w1 = wsh[e_loc + 1][d];
            const float w2 = wsh[e_loc + 2][d];
            const float w3 = wsh[e_loc + 3][d];
            acc[0][0] += xv0 * w0; acc[0][1] += xv0 * w1;
            acc[0][2] += xv0 * w2; acc[0][3] += xv0 * w3;
            acc[1][0] += xv1 * w0; acc[1][1] += xv1 * w1;
            acc[1][2] += xv1 * w2; acc[1][3] += xv1 * w3;
        }
        __syncthreads();
    }
    #pragma unroll
    for (int i = 0; i < 2; ++i)
        #pragma unroll
        for (int j = 0; j < 4; ++j)
            part[((size_t)k * S_TOK + sb + s_loc + i) * NE + e_loc + j] = acc[i][j];
}

// ------------- softmax + argmax per token (wave = token, lane = expert) -------------
__global__ __launch_bounds__(256) void softmax_top1(
    const float* __restrict__ part, int* __restrict__ idx,
    float* __restrict__ gate, float* __restrict__ me_sum)
{
    const int lane = threadIdx.x & 63;
    const int wid  = threadIdx.x >> 6;
    const int gw   = blockIdx.x * 4 + wid;    // global wave id, 0..255

    float me_acc = 0.f;
    for (int s = gw; s < S_TOK; s += 256) {
        const float l = part[(size_t)s * NE + lane]
                      + part[((size_t)S_TOK + s) * NE + lane];
        // wave max
        float m = l;
        #pragma unroll
        for (int o = 32; o; o >>= 1) m = fmaxf(m, __shfl_xor(m, o));
        const float ex = __expf(l - m);
        float sum = ex;
        #pragma unroll
        for (int o = 32; o; o >>= 1) sum += __shfl_xor(sum, o);
        // argmax with first-index tie-break (matches jnp.argmax)
        float bv = l; int bi = lane;
        #pragma unroll
        for (int o = 32; o; o >>= 1) {
            const float ov = __shfl_xor(bv, o);
            const int   oi = __shfl_xor(bi, o);
            if (ov > bv || (ov == bv && oi < bi)) { bv = ov; bi = oi; }
        }
        const float g = ex / sum;            // this lane's gate value
        me_acc += g;
        if (lane == bi) {                    // argmax lane: g == 1/sum
            idx[s]  = bi;
            gate[s] = g;
        }
    }
    atomicAdd(&me_sum[lane], me_acc);
}

// ------------- per-expert prefix scan over tokens (capacity positions) -------------
__global__ __launch_bounds__(256) void scan_expert(
    const int* __restrict__ idx, const float* __restrict__ me_sum,
    int* __restrict__ loc, float* __restrict__ prod)
{
    const int e    = blockIdx.x;
    const int tid  = threadIdx.x;
    const int lane = tid & 63;
    const int wid  = tid >> 6;
    __shared__ int wsum[4];

    int running = 0;
    for (int c = 0; c < S_TOK; c += 256) {
        const int s = c + tid;
        const bool match = (idx[s] == e);
        const unsigned long long b = __ballot(match);
        const int before = __popcll(b & ((1ULL << lane) - 1ULL));
        if (lane == 0) wsum[wid] = __popcll(b);
        __syncthreads();
        int woff = 0;
        #pragma unroll
        for (int w = 0; w < 4; ++w) if (w < wid) woff += wsum[w];
        const int tot = wsum[0] + wsum[1] + wsum[2] + wsum[3];
        if (match) {
            const int pos = running + woff + before;
            loc[s] = (pos < CAP) ? pos : -1;
        }
        running += tot;
        __syncthreads();
    }
    if (tid == 0) {
        const float me = me_sum[e] / (float)S_TOK;
        const float ce = (float)running / (float)S_TOK;
        prod[e] = me * ce;
    }
}

// ------------- sparse scatter into combine/dispatch + l_aux -------------
__global__ __launch_bounds__(256) void scatter_out(
    const int* __restrict__ idx, const int* __restrict__ loc,
    const float* __restrict__ gate, const float* __restrict__ prod,
    float* __restrict__ out)
{
    if (blockIdx.x == 0 && threadIdx.x < 64) {
        float p = prod[threadIdx.x];
        #pragma unroll
        for (int o = 32; o; o >>= 1) p += __shfl_xor(p, o);
        if (threadIdx.x == 0) out[0] = p * (float)NE;  // mean_e(me*ce)*E*E
    }
    const int s = blockIdx.x * 256 + threadIdx.x;
    const int l = loc[s];
    if (l >= 0) {
        const size_t off = ((size_t)s * NE + idx[s]) * CAP + l;
        out[1 + off] = gate[s];
        out[1 + (size_t)S_TOK * NE * CAP + off] = 1.0f;
    }
}

extern "C" void kernel_launch(void* const* d_in, const int* in_sizes, int n_in,
                              void* d_out, int out_size, void* d_ws, size_t ws_size,
                              hipStream_t stream)
{
    const float* x  = (const float*)d_in[0];
    const float* wg = (const float*)d_in[1];
    float* out = (float*)d_out;
    float* ws  = (float*)d_ws;

    float* part   = ws + OFF_PART;
    int*   idx    = (int*)(ws + OFF_IDX);
    float* gate   = ws + OFF_GATE;
    int*   loc    = (int*)(ws + OFF_LOC);
    float* me_sum = ws + OFF_MESUM;
    float* prod   = ws + OFF_PROD;

    // zero the (mostly sparse) 536 MB output + the atomic accumulator
    hipMemsetAsync(d_out, 0, (size_t)out_size * sizeof(float), stream);
    hipMemsetAsync(me_sum, 0, NE * sizeof(float), stream);

    dim3 ggrid(S_TOK / BS, KSPLIT);
    gemm_logits<<<ggrid, 256, 0, stream>>>(x, wg, part);
    softmax_top1<<<64, 256, 0, stream>>>(part, idx, gate, me_sum);
    scan_expert<<<NE, 256, 0, stream>>>(idx, me_sum, loc, prod);
    scatter_out<<<S_TOK / 256, 256, 0, stream>>>(idx, loc, gate, prod, out);
}